// Round 1
// baseline (719.891 us; speedup 1.0000x reference)
//
#include <hip/hip_runtime.h>
#include <stdint.h>

#define N_TOK 4096
#define TOPK  2
#define NEXP  8
#define HID   2048
#define INTER 1408
#define NSLOT (N_TOK * TOPK)     // 8192 token-expert pairs
#define PADROWS 128              // guard rows for tile-overrun reads
#define WELEM (NEXP * INTER * HID)

typedef _Float16 half8 __attribute__((ext_vector_type(8)));
typedef float floatx4 __attribute__((ext_vector_type(4)));

__device__ __forceinline__ void gld_lds16(const void* g, void* l) {
  // async global->LDS, 16B/lane; LDS dest = wave-uniform base + lane*16
  __builtin_amdgcn_global_load_lds(
      (const __attribute__((address_space(1))) uint32_t*)g,
      (__attribute__((address_space(3))) uint32_t*)l, 16, 0, 0);
}

// ---------------- routing: counts, offsets, compact slot lists ----------------
__global__ void route_kernel(const int* __restrict__ ids, const float* __restrict__ tw,
                             int* __restrict__ cnt, int* __restrict__ offs,
                             int* __restrict__ stok, float* __restrict__ sw) {
  __shared__ int tc[NEXP][257];
  __shared__ int eo[NEXP + 1];
  const int t = threadIdx.x;
  int lc[NEXP];
#pragma unroll
  for (int e = 0; e < NEXP; e++) lc[e] = 0;
  for (int i = 0; i < NSLOT / 256; i++) {
    int e = ids[t + 256 * i];
#pragma unroll
    for (int q = 0; q < NEXP; q++) lc[q] += (e == q) ? 1 : 0;
  }
#pragma unroll
  for (int e = 0; e < NEXP; e++) tc[e][t + 1] = lc[e];
  if (t < NEXP) tc[t][0] = 0;
  __syncthreads();
  if (t < NEXP) {  // serial scan: tc[e][j] = sum of counts of threads < j
    int run = 0;
    for (int i = 0; i <= 256; i++) { run += tc[t][i]; tc[t][i] = run; }
  }
  __syncthreads();
  if (t == 0) {
    eo[0] = 0;
    for (int e = 0; e < NEXP; e++) eo[e + 1] = eo[e] + tc[e][256];
  }
  __syncthreads();
  if (t < NEXP) { cnt[t] = tc[t][256]; offs[t] = eo[t]; }
  if (t == 0) offs[NEXP] = eo[NEXP];
  int pos[NEXP];
#pragma unroll
  for (int e = 0; e < NEXP; e++) pos[e] = eo[e] + tc[e][t];
  for (int i = 0; i < NSLOT / 256; i++) {
    int s = t + 256 * i;
    int e = ids[s];
    int p = 0;
#pragma unroll
    for (int q = 0; q < NEXP; q++)
      if (e == q) p = pos[q]++;
    stok[p] = s / TOPK;
    sw[p] = tw[s];
  }
}

// ---------------- gather tokens into contiguous fp16 A ----------------
__global__ void gather_x_kernel(const float* __restrict__ x, const int* __restrict__ stok,
                                _Float16* __restrict__ xg) {
  const int row = blockIdx.x;
  const int tok = stok[row];
  const float4* src = (const float4*)(x + (size_t)tok * HID);
  half8* dst = (half8*)(xg + (size_t)row * HID);
  const int t = threadIdx.x;  // 256 threads x 8 elems = 2048
  float4 a = src[2 * t], b = src[2 * t + 1];
  half8 h;
  h[0] = (_Float16)a.x; h[1] = (_Float16)a.y; h[2] = (_Float16)a.z; h[3] = (_Float16)a.w;
  h[4] = (_Float16)b.x; h[5] = (_Float16)b.y; h[6] = (_Float16)b.z; h[7] = (_Float16)b.w;
  dst[t] = h;
}

// ---------------- fp32 -> fp16 weight conversion ----------------
__global__ void convert_fp16_kernel(const float* __restrict__ src, _Float16* __restrict__ dst,
                                    int nelem) {
  int i = blockIdx.x * blockDim.x + threadIdx.x;
  int j = i * 8;
  if (j >= nelem) return;
  float4 a = *(const float4*)(src + j);
  float4 b = *(const float4*)(src + j + 4);
  half8 h;
  h[0] = (_Float16)a.x; h[1] = (_Float16)a.y; h[2] = (_Float16)a.z; h[3] = (_Float16)a.w;
  h[4] = (_Float16)b.x; h[5] = (_Float16)b.y; h[6] = (_Float16)b.z; h[7] = (_Float16)b.w;
  *(half8*)(dst + j) = h;
}

__global__ void zero_kernel(float4* __restrict__ p, int n4) {
  int i = blockIdx.x * blockDim.x + threadIdx.x;
  int stride = gridDim.x * blockDim.x;
  for (; i < n4; i += stride) p[i] = make_float4(0.f, 0.f, 0.f, 0.f);
}

// ---------------- m97-style GEMM: C[m,n] = sum_k A[m,k] * B[n,k] ----------------
// EPI 0: plain fp16 store (gate). EPI 2: read g from C, write silu(g)*acc (up).
// EPI 1: scatter-add weight*acc into fp32 out rows by token (down).
template <int EPI, int K, int NTOT>
__global__ __launch_bounds__(256) void gemm_kernel(
    const _Float16* __restrict__ A, const _Float16* __restrict__ B, void* __restrict__ Cout,
    const int* __restrict__ cnt, const int* __restrict__ offs,
    const int* __restrict__ stok, const float* __restrict__ sw) {
  const int e = blockIdx.z;
  const int m_cnt = cnt[e];
  const int rt = blockIdx.y;
  if (rt * 128 >= m_cnt) return;
  const int row0 = offs[e] + rt * 128;  // slot-space row
  const int col0 = blockIdx.x * 128;
  const _Float16* Be = B + (size_t)e * NTOT * K;

  __shared__ __align__(16) _Float16 As[128 * 32];
  __shared__ __align__(16) _Float16 Bs[128 * 32];

  const int tid = threadIdx.x;
  const int wave = tid >> 6;
  const int lane = tid & 63;
  const int quad = lane >> 4;
  const int l16 = lane & 15;
  const int wm = (wave >> 1) * 64;
  const int wn = (wave & 1) * 64;

  // staging: 8KB tile = 8 issues of 1024B; wave w does issues {2w, 2w+1}
  const int bo0 = (wave * 2) * 1024 + lane * 16;
  const int bo1 = bo0 + 1024;
  const int ar0 = bo0 >> 6, ak0 = (bo0 & 63) >> 1;  // row, k-offset (halfs)
  const int ar1 = bo1 >> 6, ak1 = (bo1 & 63) >> 1;
  const _Float16* Ab0 = A + (size_t)(row0 + ar0) * K + ak0;
  const _Float16* Ab1 = A + (size_t)(row0 + ar1) * K + ak1;
  const _Float16* Bb0 = Be + (size_t)(col0 + ar0) * K + ak0;
  const _Float16* Bb1 = Be + (size_t)(col0 + ar1) * K + ak1;
  char* Asl0 = (char*)As + (wave * 2) * 1024;
  char* Asl1 = Asl0 + 1024;
  char* Bsl0 = (char*)Bs + (wave * 2) * 1024;
  char* Bsl1 = Bsl0 + 1024;

  floatx4 acc[4][4];
#pragma unroll
  for (int a = 0; a < 4; a++)
#pragma unroll
    for (int b = 0; b < 4; b++) acc[a][b] = (floatx4){0.f, 0.f, 0.f, 0.f};

  for (int k0 = 0; k0 < K; k0 += 32) {
    gld_lds16(Ab0 + k0, Asl0);
    gld_lds16(Ab1 + k0, Asl1);
    gld_lds16(Bb0 + k0, Bsl0);
    gld_lds16(Bb1 + k0, Bsl1);
    __syncthreads();
    half8 af[4], bf[4];
#pragma unroll
    for (int mi = 0; mi < 4; mi++)
      af[mi] = *(const half8*)(As + (wm + mi * 16 + l16) * 32 + quad * 8);
#pragma unroll
    for (int ni = 0; ni < 4; ni++)
      bf[ni] = *(const half8*)(Bs + (wn + ni * 16 + l16) * 32 + quad * 8);
#pragma unroll
    for (int mi = 0; mi < 4; mi++)
#pragma unroll
      for (int ni = 0; ni < 4; ni++)
        acc[mi][ni] = __builtin_amdgcn_mfma_f32_16x16x32_f16(af[mi], bf[ni], acc[mi][ni], 0, 0, 0);
    __syncthreads();
  }

  const int mrem = m_cnt - rt * 128;
  // D mapping (measured m89): col = lane&15, row = (lane>>4)*4 + reg
  if constexpr (EPI == 0) {
    _Float16* C = (_Float16*)Cout;
#pragma unroll
    for (int mi = 0; mi < 4; mi++)
#pragma unroll
      for (int r = 0; r < 4; r++) {
        const int rm = wm + mi * 16 + quad * 4 + r;
        if (rm < mrem) {
          _Float16* crow = C + (size_t)(row0 + rm) * NTOT + col0 + wn;
#pragma unroll
          for (int ni = 0; ni < 4; ni++) crow[ni * 16 + l16] = (_Float16)acc[mi][ni][r];
        }
      }
  } else if constexpr (EPI == 2) {
    _Float16* C = (_Float16*)Cout;
#pragma unroll
    for (int mi = 0; mi < 4; mi++)
#pragma unroll
      for (int r = 0; r < 4; r++) {
        const int rm = wm + mi * 16 + quad * 4 + r;
        if (rm < mrem) {
          _Float16* crow = C + (size_t)(row0 + rm) * NTOT + col0 + wn;
#pragma unroll
          for (int ni = 0; ni < 4; ni++) {
            float g = (float)crow[ni * 16 + l16];
            float s = 1.0f / (1.0f + __expf(-g));
            crow[ni * 16 + l16] = (_Float16)(g * s * acc[mi][ni][r]);
          }
        }
      }
  } else {
    float* outp = (float*)Cout;
#pragma unroll
    for (int mi = 0; mi < 4; mi++)
#pragma unroll
      for (int r = 0; r < 4; r++) {
        const int rm = wm + mi * 16 + quad * 4 + r;
        if (rm < mrem) {
          const int slot = row0 + rm;
          const float wgt = sw[slot];
          float* orow = outp + (size_t)stok[slot] * NTOT + col0 + wn;
#pragma unroll
          for (int ni = 0; ni < 4; ni++) atomicAdd(&orow[ni * 16 + l16], wgt * acc[mi][ni][r]);
        }
      }
  }
}

extern "C" void kernel_launch(void* const* d_in, const int* in_sizes, int n_in,
                              void* d_out, int out_size, void* d_ws, size_t ws_size,
                              hipStream_t stream) {
  const float* x   = (const float*)d_in[0];
  const int*   ids = (const int*)d_in[1];
  const float* tw  = (const float*)d_in[2];
  const float* Wg  = (const float*)d_in[3];
  const float* Wu  = (const float*)d_in[4];
  const float* Wd  = (const float*)d_in[5];
  float* out = (float*)d_out;

  char* ws = (char*)d_ws;
  size_t p = 0;
  auto alloc = [&](size_t bytes) -> void* {
    void* r = ws + p;
    p = (p + bytes + 255) & ~(size_t)255;
    return r;
  };
  int*   cnt  = (int*)alloc(NEXP * 4);
  int*   offs = (int*)alloc((NEXP + 1) * 4);
  int*   stok = (int*)alloc(NSLOT * 4);
  float* sw   = (float*)alloc(NSLOT * 4);
  _Float16* Xg   = (_Float16*)alloc((size_t)(NSLOT + PADROWS) * HID * 2);
  _Float16* Hb   = (_Float16*)alloc((size_t)(NSLOT + PADROWS) * INTER * 2);
  _Float16* Wg16 = (_Float16*)alloc((size_t)WELEM * 2);
  _Float16* Wu16 = (_Float16*)alloc((size_t)WELEM * 2);
  _Float16* Wd16 = (_Float16*)alloc((size_t)WELEM * 2);
  (void)ws_size; (void)in_sizes; (void)n_in; (void)out_size;

  route_kernel<<<1, 256, 0, stream>>>(ids, tw, cnt, offs, stok, sw);
  gather_x_kernel<<<NSLOT, 256, 0, stream>>>(x, stok, Xg);
  const int cgrid = WELEM / 8 / 256;  // exact
  convert_fp16_kernel<<<cgrid, 256, 0, stream>>>(Wg, Wg16, WELEM);
  convert_fp16_kernel<<<cgrid, 256, 0, stream>>>(Wu, Wu16, WELEM);
  convert_fp16_kernel<<<cgrid, 256, 0, stream>>>(Wd, Wd16, WELEM);
  zero_kernel<<<2048, 256, 0, stream>>>((float4*)out, (N_TOK * HID) / 4);
  // gate: Hb = Xg @ Wg^T
  gemm_kernel<0, HID, INTER><<<dim3(INTER / 128, 32, NEXP), 256, 0, stream>>>(
      Xg, Wg16, Hb, cnt, offs, stok, sw);
  // up + fused SwiGLU: Hb = silu(Hb) * (Xg @ Wu^T)
  gemm_kernel<2, HID, INTER><<<dim3(INTER / 128, 32, NEXP), 256, 0, stream>>>(
      Xg, Wu16, Hb, cnt, offs, stok, sw);
  // down + weighted scatter-add into out
  gemm_kernel<1, INTER, HID><<<dim3(HID / 128, 32, NEXP), 256, 0, stream>>>(
      Hb, Wd16, out, cnt, offs, stok, sw);
}

// Round 2
// 628.785 us; speedup vs baseline: 1.1449x; 1.1449x over previous
//
#include <hip/hip_runtime.h>
#include <stdint.h>

#define N_TOK 4096
#define TOPK  2
#define NEXP  8
#define HID   2048
#define INTER 1408
#define NSLOT (N_TOK * TOPK)     // 8192 token-expert pairs
#define PADROWS 128              // guard rows for tile-overrun reads
#define WELEM (NEXP * INTER * HID)
#define MAXTILES 72              // worst-case sum of ceil(cnt_e/128)

typedef _Float16 half8 __attribute__((ext_vector_type(8)));
typedef float floatx4 __attribute__((ext_vector_type(4)));

__device__ __forceinline__ void gld_lds16(const void* g, void* l) {
  // async global->LDS, 16B/lane; LDS dest = wave-uniform base + lane*16
  __builtin_amdgcn_global_load_lds(
      (const __attribute__((address_space(1))) uint32_t*)g,
      (__attribute__((address_space(3))) uint32_t*)l, 16, 0, 0);
}

// s_waitcnt imm encodings (gfx9-style): vmcnt[3:0]+[15:14], exp[6:4], lgkm[11:8]
#define WAITCNT_VM6   0x0F76   // vmcnt(6), exp/lgkm don't-care
#define WAITCNT_VM4   0x0F74   // vmcnt(4)
#define WAITCNT_VM0   0x0F70   // vmcnt(0)
#define WAITCNT_LGKM0 0xC07F   // lgkmcnt(0), vmcnt/exp don't-care
#define RAW_BARRIER() asm volatile("s_barrier" ::: "memory")

// ---------------- routing: compact slot lists + balanced tile table ----------------
__global__ void route_kernel(const int* __restrict__ ids, const float* __restrict__ tw,
                             int* __restrict__ tinfo,  // [0]=ntiles; per tile: e,row0,mrem
                             int* __restrict__ stok, float* __restrict__ sw) {
  __shared__ int tc[NEXP][257];
  __shared__ int eo[NEXP + 1];
  const int t = threadIdx.x;
  int lc[NEXP];
#pragma unroll
  for (int e = 0; e < NEXP; e++) lc[e] = 0;
  for (int i = 0; i < NSLOT / 256; i++) {
    int e = ids[t + 256 * i];
#pragma unroll
    for (int q = 0; q < NEXP; q++) lc[q] += (e == q) ? 1 : 0;
  }
#pragma unroll
  for (int e = 0; e < NEXP; e++) tc[e][t + 1] = lc[e];
  if (t < NEXP) tc[t][0] = 0;
  __syncthreads();
  if (t < NEXP) {  // serial scan: tc[e][j] = counts of threads < j
    int run = 0;
    for (int i = 0; i <= 256; i++) { run += tc[t][i]; tc[t][i] = run; }
  }
  __syncthreads();
  if (t == 0) {
    eo[0] = 0;
    for (int e = 0; e < NEXP; e++) eo[e + 1] = eo[e] + tc[e][256];
    int nt = 0;
    for (int e = 0; e < NEXP; e++) {
      const int c = tc[e][256];
      for (int r0 = 0; r0 < c; r0 += 128) {
        tinfo[1 + 3 * nt] = e;
        tinfo[2 + 3 * nt] = eo[e] + r0;
        tinfo[3 + 3 * nt] = (c - r0 < 128) ? (c - r0) : 128;
        nt++;
      }
    }
    tinfo[0] = nt;
  }
  __syncthreads();
  int pos[NEXP];
#pragma unroll
  for (int e = 0; e < NEXP; e++) pos[e] = eo[e] + tc[e][t];
  for (int i = 0; i < NSLOT / 256; i++) {
    int s = t + 256 * i;
    int e = ids[s];
    int p = 0;
#pragma unroll
    for (int q = 0; q < NEXP; q++)
      if (e == q) p = pos[q]++;
    stok[p] = s / TOPK;
    sw[p] = tw[s];
  }
}

// ---------------- gather tokens into contiguous fp16 A ----------------
__global__ void gather_x_kernel(const float* __restrict__ x, const int* __restrict__ stok,
                                _Float16* __restrict__ xg) {
  const int row = blockIdx.x;
  const int tok = stok[row];
  const float4* src = (const float4*)(x + (size_t)tok * HID);
  half8* dst = (half8*)(xg + (size_t)row * HID);
  const int t = threadIdx.x;  // 256 threads x 8 elems = 2048
  float4 a = src[2 * t], b = src[2 * t + 1];
  half8 h;
  h[0] = (_Float16)a.x; h[1] = (_Float16)a.y; h[2] = (_Float16)a.z; h[3] = (_Float16)a.w;
  h[4] = (_Float16)b.x; h[5] = (_Float16)b.y; h[6] = (_Float16)b.z; h[7] = (_Float16)b.w;
  dst[t] = h;
}

// ---------------- fp32 -> fp16 weight conversion, all 3 matrices ----------------
__global__ void convert3_kernel(const float* __restrict__ s0, const float* __restrict__ s1,
                                const float* __restrict__ s2, _Float16* __restrict__ d0,
                                _Float16* __restrict__ d1, _Float16* __restrict__ d2) {
  const float* s = blockIdx.z == 0 ? s0 : (blockIdx.z == 1 ? s1 : s2);
  _Float16* d = blockIdx.z == 0 ? d0 : (blockIdx.z == 1 ? d1 : d2);
  const int j = (blockIdx.x * 256 + threadIdx.x) * 8;
  float4 a = *(const float4*)(s + j);
  float4 b = *(const float4*)(s + j + 4);
  half8 h;
  h[0] = (_Float16)a.x; h[1] = (_Float16)a.y; h[2] = (_Float16)a.z; h[3] = (_Float16)a.w;
  h[4] = (_Float16)b.x; h[5] = (_Float16)b.y; h[6] = (_Float16)b.z; h[7] = (_Float16)b.w;
  *(half8*)(d + j) = h;
}

__global__ void zero_kernel(float4* __restrict__ p, int n4) {
  int i = blockIdx.x * blockDim.x + threadIdx.x;
  int stride = gridDim.x * blockDim.x;
  for (; i < n4; i += stride) p[i] = make_float4(0.f, 0.f, 0.f, 0.f);
}

// ---------------- fused gate+up GEMM with SwiGLU epilogue ----------------
// Hb[slot, i] = silu(Xg[slot,:] . Wg[e][i,:]) * (Xg[slot,:] . Wu[e][i,:])
// 128x128 tile, BK=32, depth-2 LDS double buffer with in-flight prefetch
// across raw s_barrier (no vmcnt(0) drain).
__global__ __launch_bounds__(256, 2) void gateup_kernel(
    const _Float16* __restrict__ A, const _Float16* __restrict__ Bg,
    const _Float16* __restrict__ Bu, _Float16* __restrict__ H,
    const int* __restrict__ tinfo) {
  const int nt = tinfo[0];
  const int ty = blockIdx.y;
  if (ty >= nt) return;
  const int e    = tinfo[1 + 3 * ty];
  const int row0 = tinfo[2 + 3 * ty];
  const int mrem = tinfo[3 + 3 * ty];
  const int col0 = blockIdx.x * 128;
  const _Float16* Bge = Bg + (size_t)e * INTER * HID;
  const _Float16* Bue = Bu + (size_t)e * INTER * HID;

  __shared__ __align__(16) _Float16 As[2][128 * 32];
  __shared__ __align__(16) _Float16 Bgs[2][128 * 32];
  __shared__ __align__(16) _Float16 Bus[2][128 * 32];

  const int tid = threadIdx.x;
  const int wave = tid >> 6, lane = tid & 63;
  const int quad = lane >> 4, l16 = lane & 15;
  const int wm = (wave >> 1) * 64, wn = (wave & 1) * 64;

  // staging: each 8KB tile = 8 chunks of 1024B; wave w covers chunks {2w,2w+1}
  const int bo0 = wave * 2048 + lane * 16, bo1 = bo0 + 1024;
  const int ar0 = bo0 >> 6, ak0 = (bo0 & 63) >> 1;
  const int ar1 = bo1 >> 6, ak1 = (bo1 & 63) >> 1;
  const _Float16* Ab0 = A + (size_t)(row0 + ar0) * HID + ak0;
  const _Float16* Ab1 = A + (size_t)(row0 + ar1) * HID + ak1;
  const _Float16* Bg0 = Bge + (size_t)(col0 + ar0) * HID + ak0;
  const _Float16* Bg1 = Bge + (size_t)(col0 + ar1) * HID + ak1;
  const _Float16* Bu0 = Bue + (size_t)(col0 + ar0) * HID + ak0;
  const _Float16* Bu1 = Bue + (size_t)(col0 + ar1) * HID + ak1;

  floatx4 ag[4][4], au[4][4];
#pragma unroll
  for (int a = 0; a < 4; a++)
#pragma unroll
    for (int b = 0; b < 4; b++) {
      ag[a][b] = (floatx4){0.f, 0.f, 0.f, 0.f};
      au[a][b] = (floatx4){0.f, 0.f, 0.f, 0.f};
    }

  auto stage = [&](int kt, int buf) {  // 6 vmem issues per wave
    const int k0 = kt * 32;
    char* as = (char*)(As[buf]) + wave * 2048;
    char* bg = (char*)(Bgs[buf]) + wave * 2048;
    char* bu = (char*)(Bus[buf]) + wave * 2048;
    gld_lds16(Ab0 + k0, as);
    gld_lds16(Ab1 + k0, as + 1024);
    gld_lds16(Bg0 + k0, bg);
    gld_lds16(Bg1 + k0, bg + 1024);
    gld_lds16(Bu0 + k0, bu);
    gld_lds16(Bu1 + k0, bu + 1024);
  };

  const int NKI = HID / 32;  // 64
  stage(0, 0);
  stage(1, 1);
  for (int kt = 0; kt < NKI; ++kt) {
    const int buf = kt & 1;
    // wait until this buffer's 6 loads landed; keep next stage's 6 in flight
    if (kt < NKI - 1) __builtin_amdgcn_s_waitcnt(WAITCNT_VM6);
    else              __builtin_amdgcn_s_waitcnt(WAITCNT_VM0);
    RAW_BARRIER();  // all waves' stage(kt) visible; prefetch NOT drained
    half8 af[4], bgf[4], buf_[4];
#pragma unroll
    for (int i = 0; i < 4; ++i) {
      af[i]   = *(const half8*)(As[buf]  + (wm + i * 16 + l16) * 32 + quad * 8);
      bgf[i]  = *(const half8*)(Bgs[buf] + (wn + i * 16 + l16) * 32 + quad * 8);
      buf_[i] = *(const half8*)(Bus[buf] + (wn + i * 16 + l16) * 32 + quad * 8);
    }
    __builtin_amdgcn_s_waitcnt(WAITCNT_LGKM0);  // my frag reads complete
    RAW_BARRIER();                              // all waves done reading buf
    if (kt + 2 < NKI) stage(kt + 2, buf);       // safe to overwrite now
#pragma unroll
    for (int mi = 0; mi < 4; ++mi)
#pragma unroll
      for (int ni = 0; ni < 4; ++ni) {
        ag[mi][ni] = __builtin_amdgcn_mfma_f32_16x16x32_f16(af[mi], bgf[ni], ag[mi][ni], 0, 0, 0);
        au[mi][ni] = __builtin_amdgcn_mfma_f32_16x16x32_f16(af[mi], buf_[ni], au[mi][ni], 0, 0, 0);
      }
  }

  // D mapping (m89): col = lane&15, row = quad*4 + reg
#pragma unroll
  for (int mi = 0; mi < 4; ++mi)
#pragma unroll
    for (int r = 0; r < 4; ++r) {
      const int rm = wm + mi * 16 + quad * 4 + r;
      if (rm < mrem) {
        _Float16* hrow = H + (size_t)(row0 + rm) * INTER + col0 + wn;
#pragma unroll
        for (int ni = 0; ni < 4; ++ni) {
          float g = ag[mi][ni][r], u = au[mi][ni][r];
          float s = 1.0f / (1.0f + __expf(-g));
          hrow[ni * 16 + l16] = (_Float16)(g * s * u);
        }
      }
    }
}

// ---------------- down GEMM + weighted scatter-add ----------------
__global__ __launch_bounds__(256, 3) void down_kernel(
    const _Float16* __restrict__ A, const _Float16* __restrict__ B, float* __restrict__ out,
    const int* __restrict__ tinfo, const int* __restrict__ stok, const float* __restrict__ sw) {
  const int nt = tinfo[0];
  const int ty = blockIdx.y;
  if (ty >= nt) return;
  const int e    = tinfo[1 + 3 * ty];
  const int row0 = tinfo[2 + 3 * ty];
  const int mrem = tinfo[3 + 3 * ty];
  const int col0 = blockIdx.x * 128;
  const _Float16* Be = B + (size_t)e * HID * INTER;

  __shared__ __align__(16) _Float16 As[2][128 * 32];
  __shared__ __align__(16) _Float16 Bs[2][128 * 32];

  const int tid = threadIdx.x;
  const int wave = tid >> 6, lane = tid & 63;
  const int quad = lane >> 4, l16 = lane & 15;
  const int wm = (wave >> 1) * 64, wn = (wave & 1) * 64;

  const int bo0 = wave * 2048 + lane * 16, bo1 = bo0 + 1024;
  const int ar0 = bo0 >> 6, ak0 = (bo0 & 63) >> 1;
  const int ar1 = bo1 >> 6, ak1 = (bo1 & 63) >> 1;
  const _Float16* Ab0 = A + (size_t)(row0 + ar0) * INTER + ak0;
  const _Float16* Ab1 = A + (size_t)(row0 + ar1) * INTER + ak1;
  const _Float16* Bb0 = Be + (size_t)(col0 + ar0) * INTER + ak0;
  const _Float16* Bb1 = Be + (size_t)(col0 + ar1) * INTER + ak1;

  floatx4 acc[4][4];
#pragma unroll
  for (int a = 0; a < 4; a++)
#pragma unroll
    for (int b = 0; b < 4; b++) acc[a][b] = (floatx4){0.f, 0.f, 0.f, 0.f};

  auto stage = [&](int kt, int buf) {  // 4 vmem issues per wave
    const int k0 = kt * 32;
    char* as = (char*)(As[buf]) + wave * 2048;
    char* bs = (char*)(Bs[buf]) + wave * 2048;
    gld_lds16(Ab0 + k0, as);
    gld_lds16(Ab1 + k0, as + 1024);
    gld_lds16(Bb0 + k0, bs);
    gld_lds16(Bb1 + k0, bs + 1024);
  };

  const int NKI = INTER / 32;  // 44
  stage(0, 0);
  stage(1, 1);
  for (int kt = 0; kt < NKI; ++kt) {
    const int buf = kt & 1;
    if (kt < NKI - 1) __builtin_amdgcn_s_waitcnt(WAITCNT_VM4);
    else              __builtin_amdgcn_s_waitcnt(WAITCNT_VM0);
    RAW_BARRIER();
    half8 af[4], bf[4];
#pragma unroll
    for (int i = 0; i < 4; ++i) {
      af[i] = *(const half8*)(As[buf] + (wm + i * 16 + l16) * 32 + quad * 8);
      bf[i] = *(const half8*)(Bs[buf] + (wn + i * 16 + l16) * 32 + quad * 8);
    }
    __builtin_amdgcn_s_waitcnt(WAITCNT_LGKM0);
    RAW_BARRIER();
    if (kt + 2 < NKI) stage(kt + 2, buf);
#pragma unroll
    for (int mi = 0; mi < 4; ++mi)
#pragma unroll
      for (int ni = 0; ni < 4; ++ni)
        acc[mi][ni] = __builtin_amdgcn_mfma_f32_16x16x32_f16(af[mi], bf[ni], acc[mi][ni], 0, 0, 0);
  }

#pragma unroll
  for (int mi = 0; mi < 4; ++mi)
#pragma unroll
    for (int r = 0; r < 4; ++r) {
      const int rm = wm + mi * 16 + quad * 4 + r;
      if (rm < mrem) {
        const int slot = row0 + rm;
        const float wgt = sw[slot];
        float* orow = out + (size_t)stok[slot] * HID + col0 + wn;
#pragma unroll
        for (int ni = 0; ni < 4; ++ni) atomicAdd(&orow[ni * 16 + l16], wgt * acc[mi][ni][r]);
      }
    }
}

extern "C" void kernel_launch(void* const* d_in, const int* in_sizes, int n_in,
                              void* d_out, int out_size, void* d_ws, size_t ws_size,
                              hipStream_t stream) {
  const float* x   = (const float*)d_in[0];
  const int*   ids = (const int*)d_in[1];
  const float* tw  = (const float*)d_in[2];
  const float* Wg  = (const float*)d_in[3];
  const float* Wu  = (const float*)d_in[4];
  const float* Wd  = (const float*)d_in[5];
  float* out = (float*)d_out;

  char* ws = (char*)d_ws;
  size_t p = 0;
  auto alloc = [&](size_t bytes) -> void* {
    void* r = ws + p;
    p = (p + bytes + 255) & ~(size_t)255;
    return r;
  };
  int*   tinfo = (int*)alloc((1 + 3 * MAXTILES) * 4);
  int*   stok  = (int*)alloc(NSLOT * 4);
  float* sw    = (float*)alloc(NSLOT * 4);
  _Float16* Xg   = (_Float16*)alloc((size_t)(NSLOT + PADROWS) * HID * 2);
  _Float16* Hb   = (_Float16*)alloc((size_t)(NSLOT + PADROWS) * INTER * 2);
  _Float16* Wg16 = (_Float16*)alloc((size_t)WELEM * 2);
  _Float16* Wu16 = (_Float16*)alloc((size_t)WELEM * 2);
  _Float16* Wd16 = (_Float16*)alloc((size_t)WELEM * 2);
  (void)ws_size; (void)in_sizes; (void)n_in; (void)out_size;

  route_kernel<<<1, 256, 0, stream>>>(ids, tw, tinfo, stok, sw);
  gather_x_kernel<<<NSLOT, 256, 0, stream>>>(x, stok, Xg);
  convert3_kernel<<<dim3(WELEM / 8 / 256, 1, 3), 256, 0, stream>>>(Wg, Wu, Wd, Wg16, Wu16, Wd16);
  zero_kernel<<<2048, 256, 0, stream>>>((float4*)out, (N_TOK * HID) / 4);
  gateup_kernel<<<dim3(INTER / 128, MAXTILES), 256, 0, stream>>>(Xg, Wg16, Wu16, Hb, tinfo);
  down_kernel<<<dim3(HID / 128, MAXTILES), 256, 0, stream>>>(Hb, Wd16, out, tinfo, stok, sw);
}